// Round 3
// baseline (505.288 us; speedup 1.0000x reference)
//
#include <hip/hip_runtime.h>
#include <math.h>

#define DMODEL 1024
#define SIXD   6144
#define NHEAD  16
#define HEADD  64
#define LSEQ   1024
#define NBATCH 8
#define MROWS  8192   // NBATCH*LSEQ

typedef unsigned short ushort_t;
typedef __attribute__((ext_vector_type(8))) short bf16x8;
typedef __attribute__((ext_vector_type(4))) float f32x4;

__device__ __forceinline__ unsigned short f2bf(float f) {
  unsigned int u = __float_as_uint(f);
  u += 0x7fff + ((u >> 16) & 1);          // round-to-nearest-even
  return (unsigned short)(u >> 16);
}

__device__ __forceinline__ void gload_lds16(const void* g, void* l) {
  __builtin_amdgcn_global_load_lds(
      (const __attribute__((address_space(1))) unsigned int*)g,
      (__attribute__((address_space(3))) unsigned int*)l, 16, 0, 0);
}

// ---------------- weight transpose + cast: W[K][N] f32 -> WT[N][K] bf16 ----
__global__ void tcast_kernel(const float* __restrict__ W, ushort_t* __restrict__ WT,
                             int K, int N) {
  __shared__ float tile[32][33];
  int tx = threadIdx.x & 31, ty = threadIdx.x >> 5;
  int n0 = blockIdx.x * 32, k0 = blockIdx.y * 32;
#pragma unroll
  for (int r = 0; r < 4; ++r)
    tile[ty + 8*r][tx] = W[(size_t)(k0 + ty + 8*r) * N + n0 + tx];
  __syncthreads();
#pragma unroll
  for (int r = 0; r < 4; ++r)
    WT[(size_t)(n0 + ty + 8*r) * K + k0 + tx] = f2bf(tile[tx][ty + 8*r]);
}

// ---------------- adaLN: ssg[b][j] = silu(c[b]) @ ada_w[:,j] + ada_b[j] ----
__global__ void ada_kernel(const float* __restrict__ c, const float* __restrict__ ada_w,
                           const float* __restrict__ ada_b, float* __restrict__ ssg) {
  __shared__ float s[DMODEL];
  int b = blockIdx.y;
  int j = blockIdx.x * 256 + threadIdx.x;
  for (int i = threadIdx.x; i < DMODEL; i += 256) {
    float v = c[b * DMODEL + i];
    s[i] = v / (1.0f + __expf(-v));
  }
  __syncthreads();
  float acc = ada_b[j];
#pragma unroll 8
  for (int k = 0; k < DMODEL; ++k)
    acc = fmaf(s[k], ada_w[(size_t)k * SIXD + j], acc);
  ssg[b * SIXD + j] = acc;
}

// ---------------- LayerNorm + modulate + cast to bf16 ---------------------
__global__ __launch_bounds__(256) void ln_mod_kernel(
    const float* __restrict__ xin, const float* __restrict__ lw,
    const float* __restrict__ lb, const float* __restrict__ ssg,
    int shift_off, int scale_off, ushort_t* __restrict__ outB) {
  int row = blockIdx.x;
  int b = row >> 10;
  int tid = threadIdx.x;
  float4 v = ((const float4*)xin)[(size_t)row * 256 + tid];
  float sum = v.x + v.y + v.z + v.w;
  float sq  = v.x*v.x + v.y*v.y + v.z*v.z + v.w*v.w;
#pragma unroll
  for (int m = 32; m; m >>= 1) { sum += __shfl_xor(sum, m); sq += __shfl_xor(sq, m); }
  __shared__ float rbuf[8];
  int w = tid >> 6, lane = tid & 63;
  if (lane == 0) { rbuf[w] = sum; rbuf[4 + w] = sq; }
  __syncthreads();
  sum = rbuf[0] + rbuf[1] + rbuf[2] + rbuf[3];
  sq  = rbuf[4] + rbuf[5] + rbuf[6] + rbuf[7];
  float mu  = sum * (1.0f / 1024.0f);
  float var = sq * (1.0f / 1024.0f) - mu * mu;
  float rs  = rsqrtf(var + 1e-5f);
  const float* sg = ssg + b * SIXD;
  float vv[4] = {v.x, v.y, v.z, v.w};
  ushort4 pk;
  unsigned short* pks = (unsigned short*)&pk;
#pragma unroll
  for (int j = 0; j < 4; ++j) {
    int d = tid * 4 + j;
    float h = (vv[j] - mu) * rs * lw[d] + lb[d];
    h = h * (1.0f + sg[scale_off + d]) + sg[shift_off + d];
    pks[j] = f2bf(h);
  }
  ((ushort4*)outB)[(size_t)row * 256 + tid] = pk;
}

// ---------------- GEMM: C[M][N] = A[M][K]bf16 @ BT[N][K]bf16^T + epilogue --
// EPI: 0 = +bias -> bf16 (qkv)
//      1 = +bias, out = resid + gate*val -> f32 (proj)
//      2 = +bias, gelu -> bf16 (fc1)
//      3 = +bias, out = resid + gate*val -> f32 (fc2)
template <int EPI>
__global__ __launch_bounds__(256, 2) void gemm_kernel(
    const ushort_t* __restrict__ A, const ushort_t* __restrict__ BT,
    const float* __restrict__ bias, const float* __restrict__ ssg,
    const float* resid, float* outF, ushort_t* __restrict__ outB,
    int N, int K, int gate_off) {
  __shared__ __align__(16) char As[16384];
  __shared__ __align__(16) char Bs[16384];
  int tid = threadIdx.x, lane = tid & 63, w = tid >> 6;
  int l15 = lane & 15, g = lane >> 4;
  int m0 = blockIdx.y * 128, n0 = blockIdx.x * 128;
  int wrow = (w >> 1) * 64, wcol = (w & 1) * 64;
  f32x4 zero = {0.f, 0.f, 0.f, 0.f};
  f32x4 acc[4][4];
#pragma unroll
  for (int i = 0; i < 4; ++i)
#pragma unroll
    for (int j = 0; j < 4; ++j) acc[i][j] = zero;

  for (int k0 = 0; k0 < K; k0 += 64) {
#pragma unroll
    for (int p = 0; p < 4; ++p) {
      int flat = p * 4096 + w * 1024 + lane * 16;
      int row = flat >> 7;
      int colb = (flat & 127) ^ ((row & 7) << 4);   // inverse-swizzled source
      gload_lds16((const char*)A  + ((size_t)(m0 + row) * K + k0) * 2 + colb,
                  As + p * 4096 + w * 1024);
      gload_lds16((const char*)BT + ((size_t)(n0 + row) * K + k0) * 2 + colb,
                  Bs + p * 4096 + w * 1024);
    }
    __syncthreads();
#pragma unroll
    for (int kk = 0; kk < 2; ++kk) {
      bf16x8 af[4], bfr[4];
#pragma unroll
      for (int i = 0; i < 4; ++i) {
        int ar = wrow + i * 16 + l15;
        af[i]  = *(const bf16x8*)(As + ar * 128 + ((kk * 64 + g * 16) ^ ((ar & 7) << 4)));
        int br = wcol + i * 16 + l15;
        bfr[i] = *(const bf16x8*)(Bs + br * 128 + ((kk * 64 + g * 16) ^ ((br & 7) << 4)));
      }
#pragma unroll
      for (int i = 0; i < 4; ++i)
#pragma unroll
        for (int j = 0; j < 4; ++j)
          acc[i][j] = __builtin_amdgcn_mfma_f32_16x16x32_bf16(af[i], bfr[j], acc[i][j], 0, 0, 0);
    }
    __syncthreads();
  }
  // epilogue
#pragma unroll
  for (int i = 0; i < 4; ++i)
#pragma unroll
    for (int j = 0; j < 4; ++j)
#pragma unroll
      for (int r = 0; r < 4; ++r) {
        int grow = m0 + wrow + i * 16 + g * 4 + r;
        int gcol = n0 + wcol + j * 16 + l15;
        float v = acc[i][j][r] + bias[gcol];
        if (EPI == 0) {
          outB[(size_t)grow * N + gcol] = f2bf(v);
        } else if (EPI == 1 || EPI == 3) {
          int bb = grow >> 10;
          float gate = ssg[bb * SIXD + gate_off + gcol];
          size_t idx = (size_t)grow * N + gcol;   // N==1024 here
          outF[idx] = resid[idx] + gate * v;
        } else {  // gelu tanh-approx
          float u = v;
          float t = 0.7978845608028654f * (u + 0.044715f * u * u * u);
          float e = __expf(2.0f * t);
          float th = 1.0f - 2.0f / (e + 1.0f);
          outB[(size_t)grow * N + gcol] = f2bf(0.5f * u * (1.0f + th));
        }
      }
}

// ---------------- flash attention -----------------------------------------
// grid (16 q-tiles, 128 b*h), 256 threads. Wave w owns q rows qt*64+w*16..+15.
__global__ __launch_bounds__(256, 2) void attn_kernel(
    const ushort_t* __restrict__ qkv,   // [8192][3072] bf16 (q|k|v)
    ushort_t* __restrict__ aout) {      // [8192][1024] bf16
  __shared__ __align__(16) char Ksm[8192];   // K tile [64 kv][64 d], swizzled
  __shared__ __align__(16) char Vsm[8192];   // V^T tile [64 d][64 kv], swizzled
  __shared__ __align__(16) char Psm[8192];   // per-wave P [16][64], swizzled
  int tid = threadIdx.x, lane = tid & 63, w = tid >> 6;
  int l15 = lane & 15, g = lane >> 4;
  int qt = blockIdx.x;
  int bh = blockIdx.y;
  int b = bh >> 4, h = bh & 15;

  // Q fragments (held in regs across all kv tiles)
  bf16x8 aq[2];
  {
    int qrow = qt * 64 + w * 16 + l15;
    const short* qp = (const short*)qkv + (size_t)(b * LSEQ + qrow) * 3072 + h * 64 + g * 8;
    aq[0] = *(const bf16x8*)qp;
    aq[1] = *(const bf16x8*)(qp + 32);
  }
  f32x4 zero = {0.f, 0.f, 0.f, 0.f};
  f32x4 o[4] = {zero, zero, zero, zero};
  float mrow[4] = {-INFINITY, -INFINITY, -INFINITY, -INFINITY};
  float lrow[4] = {0.f, 0.f, 0.f, 0.f};
  const float scale = 0.125f;  // 1/sqrt(64)

  for (int t = 0; t < 16; ++t) {
    int kv0 = t * 64;
    // stage K tile via global_load_lds (pre-swizzled source)
#pragma unroll
    for (int p = 0; p < 2; ++p) {
      int flat = p * 4096 + w * 1024 + lane * 16;
      int row = flat >> 7;
      int colb = (flat & 127) ^ ((row & 7) << 4);
      const char* src = (const char*)qkv +
          ((size_t)(b * LSEQ + kv0 + row) * 3072 + 1024 + h * 64) * 2 + colb;
      gload_lds16(src, Ksm + p * 4096 + w * 1024);
    }
    // stage V transposed (reg round-trip, scattered bf16 writes)
#pragma unroll
    for (int i = 0; i < 2; ++i) {
      int flat = tid + 256 * i;         // 512 chunks of 8 elems
      int kv = flat >> 3, dc = flat & 7;
      const short* vp = (const short*)qkv +
          (size_t)(b * LSEQ + kv0 + kv) * 3072 + 2048 + h * 64 + dc * 8;
      bf16x8 vv = *(const bf16x8*)vp;
#pragma unroll
      for (int j = 0; j < 8; ++j) {
        int d = dc * 8 + j;
        *(short*)(Vsm + d * 128 + ((kv * 2) ^ ((d & 7) << 4))) = vv[j];
      }
    }
    __syncthreads();
    // S = Q @ K^T
    f32x4 s[4] = {zero, zero, zero, zero};
#pragma unroll
    for (int c = 0; c < 4; ++c)
#pragma unroll
      for (int kk = 0; kk < 2; ++kk) {
        int key = c * 16 + l15;
        bf16x8 bk = *(const bf16x8*)(Ksm + key * 128 + ((kk * 64 + g * 16) ^ ((key & 7) << 4)));
        s[c] = __builtin_amdgcn_mfma_f32_16x16x32_bf16(aq[kk], bk, s[c], 0, 0, 0);
      }
    // online softmax (rows g*4+r, 16-lane group reduce)
    float pf[4][4];
#pragma unroll
    for (int r = 0; r < 4; ++r) {
      float mx = -INFINITY;
#pragma unroll
      for (int c = 0; c < 4; ++c) { s[c][r] *= scale; mx = fmaxf(mx, s[c][r]); }
      mx = fmaxf(mx, __shfl_xor(mx, 1)); mx = fmaxf(mx, __shfl_xor(mx, 2));
      mx = fmaxf(mx, __shfl_xor(mx, 4)); mx = fmaxf(mx, __shfl_xor(mx, 8));
      float mnew = fmaxf(mrow[r], mx);
      float alpha = __expf(mrow[r] - mnew);
      float sump = 0.f;
#pragma unroll
      for (int c = 0; c < 4; ++c) {
        float p = __expf(s[c][r] - mnew);
        pf[c][r] = p; sump += p;
      }
      sump += __shfl_xor(sump, 1); sump += __shfl_xor(sump, 2);
      sump += __shfl_xor(sump, 4); sump += __shfl_xor(sump, 8);
      lrow[r] = lrow[r] * alpha + sump;
      mrow[r] = mnew;
#pragma unroll
      for (int n = 0; n < 4; ++n) o[n][r] *= alpha;
    }
    // P -> LDS (bf16, per-wave region, swizzled)
    char* pb = Psm + w * 2048;
#pragma unroll
    for (int c = 0; c < 4; ++c)
#pragma unroll
      for (int r = 0; r < 4; ++r) {
        int row = g * 4 + r;
        int colb = (c * 16 + l15) * 2;
        *(short*)(pb + row * 128 + (colb ^ ((row & 7) << 4))) = (short)f2bf(pf[c][r]);
      }
    // O += P @ V
#pragma unroll
    for (int kk = 0; kk < 2; ++kk) {
      bf16x8 ap = *(const bf16x8*)(pb + l15 * 128 + ((kk * 64 + g * 16) ^ ((l15 & 7) << 4)));
#pragma unroll
      for (int n = 0; n < 4; ++n) {
        int d = n * 16 + l15;
        bf16x8 bv = *(const bf16x8*)(Vsm + d * 128 + ((kk * 64 + g * 16) ^ ((d & 7) << 4)));
        o[n] = __builtin_amdgcn_mfma_f32_16x16x32_bf16(ap, bv, o[n], 0, 0, 0);
      }
    }
    __syncthreads();
  }
  // epilogue: O / l
#pragma unroll
  for (int r = 0; r < 4; ++r) {
    float rl = 1.0f / lrow[r];
    int qrow = qt * 64 + w * 16 + g * 4 + r;
#pragma unroll
    for (int n = 0; n < 4; ++n) {
      int d = h * 64 + n * 16 + l15;
      aout[(size_t)(b * LSEQ + qrow) * 1024 + d] = f2bf(o[n][r] * rl);
    }
  }
}

// ---------------- launch ---------------------------------------------------
extern "C" void kernel_launch(void* const* d_in, const int* in_sizes, int n_in,
                              void* d_out, int out_size, void* d_ws, size_t ws_size,
                              hipStream_t stream) {
  const float* x      = (const float*)d_in[0];
  const float* c      = (const float*)d_in[1];
  const float* ln1_w  = (const float*)d_in[2];
  const float* ln1_b  = (const float*)d_in[3];
  const float* ln2_w  = (const float*)d_in[4];
  const float* ln2_b  = (const float*)d_in[5];
  const float* ada_w  = (const float*)d_in[6];
  const float* ada_b  = (const float*)d_in[7];
  const float* qkv_w  = (const float*)d_in[8];
  const float* qkv_b  = (const float*)d_in[9];
  const float* proj_w = (const float*)d_in[10];
  const float* proj_b = (const float*)d_in[11];
  const float* fc1_w  = (const float*)d_in[12];
  const float* fc1_b  = (const float*)d_in[13];
  const float* fc2_w  = (const float*)d_in[14];
  const float* fc2_b  = (const float*)d_in[15];
  float* out = (float*)d_out;
  char* ws = (char*)d_ws;

  // workspace layout (bytes); high-water = 109,248,512 (~104.2 MB)
  // abuf aliases hbuf (ln1 output dead after qkv GEMM; stream-ordered).
  ushort_t* qkvT  = (ushort_t*)(ws + 0);          // [3072][1024] bf16   6.0 MB
  ushort_t* projT = (ushort_t*)(ws + 6291456);    // [1024][1024]        2.0 MB
  ushort_t* fc1T  = (ushort_t*)(ws + 8388608);    // [4096][1024]        8.0 MB
  ushort_t* fc2T  = (ushort_t*)(ws + 16777216);   // [1024][4096]        8.0 MB
  float*    ssg   = (float*)(ws + 25165824);      // [8][6144] f32       0.2 MB
  ushort_t* hbuf  = (ushort_t*)(ws + 25362432);   // [8192][1024] bf16  16.0 MB
  ushort_t* abuf  = hbuf;                         // alias (see above)
  ushort_t* qkvb  = (ushort_t*)(ws + 42139648);   // [8192][4096] max   64.0 MB
  if (ws_size < (size_t)109248512) return;        // guard: avoid OOB -> GPU fault

  tcast_kernel<<<dim3(96, 32),  256, 0, stream>>>(qkv_w,  qkvT, 1024, 3072);
  tcast_kernel<<<dim3(32, 32),  256, 0, stream>>>(proj_w, projT, 1024, 1024);
  tcast_kernel<<<dim3(128, 32), 256, 0, stream>>>(fc1_w,  fc1T, 1024, 4096);
  tcast_kernel<<<dim3(32, 128), 256, 0, stream>>>(fc2_w,  fc2T, 4096, 1024);
  ada_kernel<<<dim3(24, 8), 256, 0, stream>>>(c, ada_w, ada_b, ssg);

  ln_mod_kernel<<<8192, 256, 0, stream>>>(x, ln1_w, ln1_b, ssg, 0, 1024, hbuf);
  gemm_kernel<0><<<dim3(24, 64), 256, 0, stream>>>(hbuf, qkvT, qkv_b, nullptr,
                                                   nullptr, nullptr, qkvb, 3072, 1024, 0);
  attn_kernel<<<dim3(16, 128), 256, 0, stream>>>(qkvb, abuf);
  gemm_kernel<1><<<dim3(8, 64), 256, 0, stream>>>(abuf, projT, proj_b, ssg,
                                                  x, out, nullptr, 1024, 1024, 2048);
  ln_mod_kernel<<<8192, 256, 0, stream>>>(out, ln2_w, ln2_b, ssg, 3072, 4096, hbuf);
  gemm_kernel<2><<<dim3(32, 64), 256, 0, stream>>>(hbuf, fc1T, fc1_b, nullptr,
                                                   nullptr, nullptr, qkvb, 4096, 1024, 0);
  gemm_kernel<3><<<dim3(8, 64), 256, 0, stream>>>(qkvb, fc2T, fc2_b, ssg,
                                                  out, out, nullptr, 1024, 4096, 5120);
}

// Round 5
// 475.816 us; speedup vs baseline: 1.0619x; 1.0619x over previous
//
#include <hip/hip_runtime.h>
#include <math.h>

#define DMODEL 1024
#define SIXD   6144
#define NHEAD  16
#define HEADD  64
#define LSEQ   1024
#define NBATCH 8
#define MROWS  8192   // NBATCH*LSEQ

typedef unsigned short ushort_t;
typedef __attribute__((ext_vector_type(8))) short bf16x8;
typedef __attribute__((ext_vector_type(4))) float f32x4;

__device__ __forceinline__ unsigned short f2bf(float f) {
  unsigned int u = __float_as_uint(f);
  u += 0x7fff + ((u >> 16) & 1);          // round-to-nearest-even
  return (unsigned short)(u >> 16);
}

__device__ __forceinline__ void gload_lds16(const void* g, void* l) {
  __builtin_amdgcn_global_load_lds(
      (const __attribute__((address_space(1))) unsigned int*)g,
      (__attribute__((address_space(3))) unsigned int*)l, 16, 0, 0);
}

// ---------------- weight transpose + cast: W[K][N] f32 -> WT[N][K] bf16 ----
__global__ void tcast_kernel(const float* __restrict__ W, ushort_t* __restrict__ WT,
                             int K, int N) {
  __shared__ float tile[32][33];
  int tx = threadIdx.x & 31, ty = threadIdx.x >> 5;
  int n0 = blockIdx.x * 32, k0 = blockIdx.y * 32;
#pragma unroll
  for (int r = 0; r < 4; ++r)
    tile[ty + 8*r][tx] = W[(size_t)(k0 + ty + 8*r) * N + n0 + tx];
  __syncthreads();
#pragma unroll
  for (int r = 0; r < 4; ++r)
    WT[(size_t)(n0 + ty + 8*r) * K + k0 + tx] = f2bf(tile[tx][ty + 8*r]);
}

// ---------------- adaLN: ssg[b][j] = silu(c[b]) @ ada_w[:,j] + ada_b[j] ----
__global__ void ada_kernel(const float* __restrict__ c, const float* __restrict__ ada_w,
                           const float* __restrict__ ada_b, float* __restrict__ ssg) {
  __shared__ float s[DMODEL];
  int b = blockIdx.y;
  int j = blockIdx.x * 256 + threadIdx.x;
  for (int i = threadIdx.x; i < DMODEL; i += 256) {
    float v = c[b * DMODEL + i];
    s[i] = v / (1.0f + __expf(-v));
  }
  __syncthreads();
  float acc = ada_b[j];
#pragma unroll 8
  for (int k = 0; k < DMODEL; ++k)
    acc = fmaf(s[k], ada_w[(size_t)k * SIXD + j], acc);
  ssg[b * SIXD + j] = acc;
}

// ---------------- LayerNorm + modulate + cast to bf16 ---------------------
__global__ __launch_bounds__(256) void ln_mod_kernel(
    const float* __restrict__ xin, const float* __restrict__ lw,
    const float* __restrict__ lb, const float* __restrict__ ssg,
    int shift_off, int scale_off, ushort_t* __restrict__ outB) {
  int row = blockIdx.x;
  int b = row >> 10;
  int tid = threadIdx.x;
  float4 v = ((const float4*)xin)[(size_t)row * 256 + tid];
  float sum = v.x + v.y + v.z + v.w;
  float sq  = v.x*v.x + v.y*v.y + v.z*v.z + v.w*v.w;
#pragma unroll
  for (int m = 32; m; m >>= 1) { sum += __shfl_xor(sum, m); sq += __shfl_xor(sq, m); }
  __shared__ float rbuf[8];
  int w = tid >> 6, lane = tid & 63;
  if (lane == 0) { rbuf[w] = sum; rbuf[4 + w] = sq; }
  __syncthreads();
  sum = rbuf[0] + rbuf[1] + rbuf[2] + rbuf[3];
  sq  = rbuf[4] + rbuf[5] + rbuf[6] + rbuf[7];
  float mu  = sum * (1.0f / 1024.0f);
  float var = sq * (1.0f / 1024.0f) - mu * mu;
  float rs  = rsqrtf(var + 1e-5f);
  const float* sg = ssg + b * SIXD;
  float vv[4] = {v.x, v.y, v.z, v.w};
  ushort4 pk;
  unsigned short* pks = (unsigned short*)&pk;
#pragma unroll
  for (int j = 0; j < 4; ++j) {
    int d = tid * 4 + j;
    float h = (vv[j] - mu) * rs * lw[d] + lb[d];
    h = h * (1.0f + sg[scale_off + d]) + sg[shift_off + d];
    pks[j] = f2bf(h);
  }
  ((ushort4*)outB)[(size_t)row * 256 + tid] = pk;
}

// ---------------- GEMM: C[M][N] = A[M][K]bf16 @ BT[N][K]bf16^T + epilogue --
template <int EPI>
__global__ __launch_bounds__(256, 2) void gemm_kernel(
    const ushort_t* __restrict__ A, const ushort_t* __restrict__ BT,
    const float* __restrict__ bias, const float* __restrict__ ssg,
    const float* resid, float* outF, ushort_t* __restrict__ outB,
    int N, int K, int gate_off) {
  __shared__ __align__(16) char As[16384];
  __shared__ __align__(16) char Bs[16384];
  int tid = threadIdx.x, lane = tid & 63, w = tid >> 6;
  int l15 = lane & 15, g = lane >> 4;
  int m0 = blockIdx.y * 128, n0 = blockIdx.x * 128;
  int wrow = (w >> 1) * 64, wcol = (w & 1) * 64;
  f32x4 zero = {0.f, 0.f, 0.f, 0.f};
  f32x4 acc[4][4];
#pragma unroll
  for (int i = 0; i < 4; ++i)
#pragma unroll
    for (int j = 0; j < 4; ++j) acc[i][j] = zero;

  for (int k0 = 0; k0 < K; k0 += 64) {
#pragma unroll
    for (int p = 0; p < 4; ++p) {
      int flat = p * 4096 + w * 1024 + lane * 16;
      int row = flat >> 7;
      int colb = (flat & 127) ^ ((row & 7) << 4);   // inverse-swizzled source
      gload_lds16((const char*)A  + ((size_t)(m0 + row) * K + k0) * 2 + colb,
                  As + p * 4096 + w * 1024);
      gload_lds16((const char*)BT + ((size_t)(n0 + row) * K + k0) * 2 + colb,
                  Bs + p * 4096 + w * 1024);
    }
    __syncthreads();
#pragma unroll
    for (int kk = 0; kk < 2; ++kk) {
      bf16x8 af[4], bfr[4];
#pragma unroll
      for (int i = 0; i < 4; ++i) {
        int ar = wrow + i * 16 + l15;
        af[i]  = *(const bf16x8*)(As + ar * 128 + ((kk * 64 + g * 16) ^ ((ar & 7) << 4)));
        int br = wcol + i * 16 + l15;
        bfr[i] = *(const bf16x8*)(Bs + br * 128 + ((kk * 64 + g * 16) ^ ((br & 7) << 4)));
      }
#pragma unroll
      for (int i = 0; i < 4; ++i)
#pragma unroll
        for (int j = 0; j < 4; ++j)
          acc[i][j] = __builtin_amdgcn_mfma_f32_16x16x32_bf16(af[i], bfr[j], acc[i][j], 0, 0, 0);
    }
    __syncthreads();
  }
  // epilogue
#pragma unroll
  for (int i = 0; i < 4; ++i)
#pragma unroll
    for (int j = 0; j < 4; ++j)
#pragma unroll
      for (int r = 0; r < 4; ++r) {
        int grow = m0 + wrow + i * 16 + g * 4 + r;
        int gcol = n0 + wcol + j * 16 + l15;
        float v = acc[i][j][r] + bias[gcol];
        if (EPI == 0) {
          outB[(size_t)grow * N + gcol] = f2bf(v);
        } else if (EPI == 1 || EPI == 3) {
          int bb = grow >> 10;
          float gate = ssg[bb * SIXD + gate_off + gcol];
          size_t idx = (size_t)grow * N + gcol;   // N==1024 here
          outF[idx] = resid[idx] + gate * v;
        } else {  // gelu tanh-approx
          float u = v;
          float t = 0.7978845608028654f * (u + 0.044715f * u * u * u);
          float e = __expf(2.0f * t);
          float th = 1.0f - 2.0f / (e + 1.0f);
          outB[(size_t)grow * N + gcol] = f2bf(0.5f * u * (1.0f + th));
        }
      }
}

// ---------------- flash attention (swapped QK^T, in-reg P, scatter V^T) ---
// grid (16 q-tiles of 64 rows, 128 b*h), 256 threads (4 waves x 16 q-rows).
// BISECTION: V path = round-3-verified scatter V^T + swizzled b128 reads;
// P path = round-4 in-register exchange. If this fails, exchange is the bug.
__global__ __launch_bounds__(256, 2) void attn_kernel(
    const ushort_t* __restrict__ qkv,   // [8192][3072] bf16 (q|k|v)
    ushort_t* __restrict__ aout) {      // [8192][1024] bf16
  // K dbuf [0,16384) ; V^T dbuf [16384,32768) ; alpha [32768,+256)
  __shared__ __align__(16) char SM[33024];
  float* alphab = (float*)(SM + 32768);
  int tid = threadIdx.x, lane = tid & 63, w = tid >> 6;
  int l15 = lane & 15, g = lane >> 4;
  int qt = blockIdx.x, bh = blockIdx.y;
  int b = bh >> 4, h = bh & 15;

  // Q fragments (B operand): lane holds Q[q = w*16 + l15][d = ks*32 + g*8 + j]
  bf16x8 aq[2];
  {
    int qrow = qt * 64 + w * 16 + l15;
    const short* qp = (const short*)qkv + (size_t)(b * LSEQ + qrow) * 3072 + h * 64 + g * 8;
    aq[0] = *(const bf16x8*)qp;
    aq[1] = *(const bf16x8*)(qp + 32);
  }

  // K staging source (pre-swizzled; tile-invariant part)
  const char* ksrc[2];
#pragma unroll
  for (int p = 0; p < 2; ++p) {
    int flat = p * 4096 + w * 1024 + lane * 16;
    int row = flat >> 7;
    int colb = (flat & 127) ^ ((row & 7) << 4);
    ksrc[p] = (const char*)qkv + ((size_t)(b * LSEQ + row) * 3072 + 1024 + h * 64) * 2 + colb;
  }
  // V chunk sources (tile-invariant): chunk i: flat = tid + 256*i
  const short* vsrc[2];
  int vkv[2], vdc[2];
#pragma unroll
  for (int i = 0; i < 2; ++i) {
    int flat = tid + 256 * i;
    vkv[i] = flat >> 3;
    vdc[i] = flat & 7;
    vsrc[i] = (const short*)qkv + (size_t)(b * LSEQ + vkv[i]) * 3072 + 2048 + h * 64 + vdc[i] * 8;
  }

  f32x4 zero = {0.f, 0.f, 0.f, 0.f};
  f32x4 o[4] = {zero, zero, zero, zero};
  float mrow = -INFINITY;   // running max in log2-units (scaled)
  float lrow = 0.f;
  const float sc = 0.18033688f;  // (1/sqrt(64)) * log2(e)

  // prologue: stage K0 + V^T0 into buffer 0
#pragma unroll
  for (int p = 0; p < 2; ++p) gload_lds16(ksrc[p], SM + p * 4096 + w * 1024);
#pragma unroll
  for (int i = 0; i < 2; ++i) {
    bf16x8 vv = *(const bf16x8*)vsrc[i];
    char* vb = SM + 16384;
#pragma unroll
    for (int j = 0; j < 8; ++j) {
      int d = vdc[i] * 8 + j;
      *(short*)(vb + d * 128 + ((vkv[i] * 2) ^ ((d & 7) << 4))) = vv[j];
    }
  }
  __syncthreads();

  for (int t = 0; t < 16; ++t) {
    int cur = t & 1;
    bf16x8 vn[2];
    if (t < 15) {   // prefetch K(t+1) to LDS, V(t+1) to regs
      size_t koff = (size_t)(t + 1) * (64 * 3072 * 2);
#pragma unroll
      for (int p = 0; p < 2; ++p)
        gload_lds16(ksrc[p] + koff, SM + (cur ^ 1) * 8192 + p * 4096 + w * 1024);
#pragma unroll
      for (int i = 0; i < 2; ++i)
        vn[i] = *(const bf16x8*)(vsrc[i] + (size_t)(t + 1) * (64 * 3072));
    }
    // ---- S^T = K @ Q^T : 8 mfma, A = K-frag (rows=keys), B = Q ----
    f32x4 s4[4] = {zero, zero, zero, zero};
#pragma unroll
    for (int c = 0; c < 4; ++c)
#pragma unroll
      for (int ks = 0; ks < 2; ++ks) {
        int key = c * 16 + l15;
        bf16x8 ak = *(const bf16x8*)(SM + cur * 8192 + key * 128 +
                                     ((ks * 64 + g * 16) ^ ((key & 7) << 4)));
        s4[c] = __builtin_amdgcn_mfma_f32_16x16x32_bf16(ak, aq[ks], s4[c], 0, 0, 0);
      }
    // ---- online softmax: lane owns q = l15; reduce over 4 g-lanes ----
    float z[16], mx = -INFINITY;
#pragma unroll
    for (int c = 0; c < 4; ++c)
#pragma unroll
      for (int r = 0; r < 4; ++r) {
        float t2 = s4[c][r] * sc;
        z[c * 4 + r] = t2;
        mx = fmaxf(mx, t2);
      }
    mx = fmaxf(mx, __shfl_xor(mx, 16));
    mx = fmaxf(mx, __shfl_xor(mx, 32));
    bool need = __any(mx > mrow);
    if (need) {
      float mnew = fmaxf(mrow, mx);
      float alpha = exp2f(mrow - mnew);
      mrow = mnew;
      if (lane < 16) alphab[w * 16 + lane] = alpha;
      lrow *= alpha;
    }
    float p16[16], sump = 0.f;
#pragma unroll
    for (int i = 0; i < 16; ++i) {
      float p = exp2f(z[i] - mrow);
      p16[i] = p;
      sump += p;
    }
    sump += __shfl_xor(sump, 16);
    sump += __shfl_xor(sump, 32);
    lrow += sump;
    if (need) {
      f32x4 av = *(const f32x4*)&alphab[w * 16 + g * 4];
#pragma unroll
      for (int nb = 0; nb < 4; ++nb)
#pragma unroll
        for (int r = 0; r < 4; ++r) o[nb][r] *= av[r];
    }
    // ---- pack P to bf16 pairs: pk[c*2+m] = (P[r=2m+1]<<16)|P[r=2m] ----
    unsigned pk[8];
#pragma unroll
    for (int c = 0; c < 4; ++c)
#pragma unroll
      for (int m = 0; m < 2; ++m)
        asm("v_cvt_pk_bf16_f32 %0, %1, %2"
            : "=v"(pk[c * 2 + m]) : "v"(p16[c * 4 + 2 * m]), "v"(p16[c * 4 + 2 * m + 1]));
    // ---- exchange: build PV A-frags (lane q = l15, k = kb*32 + g*8 + j) ----
    unsigned pa[2][4];
    int gl = (g & 1) * 2;
#pragma unroll
    for (int kb = 0; kb < 2; ++kb)
#pragma unroll
      for (int wv = 0; wv < 4; ++wv) {
        int srcl = l15 + (gl + (wv >> 1)) * 16;
        unsigned vA = (unsigned)__shfl((int)pk[kb * 4 + (wv & 1)], srcl);
        unsigned vB = (unsigned)__shfl((int)pk[kb * 4 + 2 + (wv & 1)], srcl);
        pa[kb][wv] = (g >> 1) ? vB : vA;
      }
    // ---- scatter V(t+1) into V^T buffer cur^1 (round-3-verified pattern) --
    if (t < 15) {
      char* vb = SM + 16384 + (cur ^ 1) * 8192;
#pragma unroll
      for (int i = 0; i < 2; ++i)
#pragma unroll
        for (int j = 0; j < 8; ++j) {
          int d = vdc[i] * 8 + j;
          *(short*)(vb + d * 128 + ((vkv[i] * 2) ^ ((d & 7) << 4))) = vn[i][j];
        }
    }
    // ---- O += P @ V (bv: round-3-verified swizzled b128 reads) ----
    union PU { unsigned u[4]; bf16x8 v; };
    PU pu0, pu1;
#pragma unroll
    for (int i = 0; i < 4; ++i) { pu0.u[i] = pa[0][i]; pu1.u[i] = pa[1][i]; }
#pragma unroll
    for (int kb = 0; kb < 2; ++kb)
#pragma unroll
      for (int nb = 0; nb < 4; ++nb) {
        int d = nb * 16 + l15;
        bf16x8 bv = *(const bf16x8*)(SM + 16384 + cur * 8192 + d * 128 +
                                     ((kb * 64 + g * 16) ^ ((d & 7) << 4)));
        o[nb] = __builtin_amdgcn_mfma_f32_16x16x32_bf16(kb ? pu1.v : pu0.v, bv, o[nb], 0, 0, 0);
      }
    __syncthreads();   // drains K prefetch (vmcnt) + V^T scatter; cur flip safe
  }
  // ---- epilogue: O / l (row-indexed via per-wave LDS broadcast) ----
  if (lane < 16) alphab[w * 16 + lane] = 1.0f / lrow;
  f32x4 rl = *(const f32x4*)&alphab[w * 16 + g * 4];
#pragma unroll
  for (int nb = 0; nb < 4; ++nb)
#pragma unroll
    for (int r = 0; r < 4; ++r) {
      int qrow = qt * 64 + w * 16 + g * 4 + r;
      aout[(size_t)(b * LSEQ + qrow) * 1024 + h * 64 + nb * 16 + l15] =
          f2bf(o[nb][r] * rl[r]);
    }
}

// ---------------- launch ---------------------------------------------------
extern "C" void kernel_launch(void* const* d_in, const int* in_sizes, int n_in,
                              void* d_out, int out_size, void* d_ws, size_t ws_size,
                              hipStream_t stream) {
  const float* x      = (const float*)d_in[0];
  const float* c      = (const float*)d_in[1];
  const float* ln1_w  = (const float*)d_in[2];
  const float* ln1_b  = (const float*)d_in[3];
  const float* ln2_w  = (const float*)d_in[4];
  const float* ln2_b  = (const float*)d_in[5];
  const float* ada_w  = (const float*)d_in[6];
  const float* ada_b  = (const float*)d_in[7];
  const float* qkv_w  = (const float*)d_in[8];
  const float* qkv_b  = (const float*)d_in[9];
  const float* proj_w = (const float*)d_in[10];
  const float* proj_b = (const float*)d_in[11];
  const float* fc1_w  = (const float*)d_in[12];
  const float* fc1_b  = (const float*)d_in[13];
  const float* fc2_w  = (const float*)d_in[14];
  const float* fc2_b  = (const float*)d_in[15];
  float* out = (float*)d_out;
  char* ws = (char*)d_ws;

  // workspace layout (bytes); high-water = 109,248,512 (~104.2 MB)
  ushort_t* qkvT  = (ushort_t*)(ws + 0);          // [3072][1024] bf16   6.0 MB
  ushort_t* projT = (ushort_t*)(ws + 6291456);    // [1024][1024]        2.0 MB
  ushort_t* fc1T  = (ushort_t*)(ws + 8388608);    // [4096][1024]        8.0 MB
  ushort_t* fc2T  = (ushort_t*)(ws + 16777216);   // [1024][4096]        8.0 MB
  float*    ssg   = (float*)(ws + 25165824);      // [8][6144] f32       0.2 MB
  ushort_t* hbuf  = (ushort_t*)(ws + 25362432);   // [8192][1024] bf16  16.0 MB
  ushort_t* abuf  = hbuf;                         // alias (ln1 out dead by then)
  ushort_t* qkvb  = (ushort_t*)(ws + 42139648);   // [8192][4096] max   64.0 MB
  if (ws_size < (size_t)109248512) return;        // guard: avoid OOB -> GPU fault

  tcast_kernel<<<dim3(96, 32),  256, 0, stream>>>(qkv_w,  qkvT, 1024, 3072);
  tcast_kernel<<<dim3(32, 32),  256, 0, stream>>>(proj_w, projT, 1024, 1024);
  tcast_kernel<<<dim3(128, 32), 256, 0, stream>>>(fc1_w,  fc1T, 1024, 4096);
  tcast_kernel<<<dim3(32, 128), 256, 0, stream>>>(fc2_w,  fc2T, 4096, 1024);
  ada_kernel<<<dim3(24, 8), 256, 0, stream>>>(c, ada_w, ada_b, ssg);

  ln_mod_kernel<<<8192, 256, 0, stream>>>(x, ln1_w, ln1_b, ssg, 0, 1024, hbuf);
  gemm_kernel<0><<<dim3(24, 64), 256, 0, stream>>>(hbuf, qkvT, qkv_b, nullptr,
                                                   nullptr, nullptr, qkvb, 3072, 1024, 0);
  attn_kernel<<<dim3(16, 128), 256, 0, stream>>>(qkvb, abuf);
  gemm_kernel<1><<<dim3(8, 64), 256, 0, stream>>>(abuf, projT, proj_b, ssg,
                                                  x, out, nullptr, 1024, 1024, 2048);
  ln_mod_kernel<<<8192, 256, 0, stream>>>(out, ln2_w, ln2_b, ssg, 3072, 4096, hbuf);
  gemm_kernel<2><<<dim3(32, 64), 256, 0, stream>>>(hbuf, fc1T, fc1_b, nullptr,
                                                   nullptr, nullptr, qkvb, 4096, 1024, 0);
  gemm_kernel<3><<<dim3(8, 64), 256, 0, stream>>>(qkvb, fc2T, fc2_b, ssg,
                                                  out, out, nullptr, 1024, 4096, 5120);
}

// Round 6
// 443.173 us; speedup vs baseline: 1.1402x; 1.0737x over previous
//
#include <hip/hip_runtime.h>
#include <math.h>

#define DMODEL 1024
#define SIXD   6144
#define NHEAD  16
#define HEADD  64
#define LSEQ   1024
#define NBATCH 8
#define MROWS  8192   // NBATCH*LSEQ

typedef unsigned short ushort_t;
typedef __attribute__((ext_vector_type(8))) short bf16x8;
typedef __attribute__((ext_vector_type(4))) float f32x4;

__device__ __forceinline__ unsigned short f2bf(float f) {
  unsigned int u = __float_as_uint(f);
  u += 0x7fff + ((u >> 16) & 1);          // round-to-nearest-even
  return (unsigned short)(u >> 16);
}

__device__ __forceinline__ void gload_lds16(const void* g, void* l) {
  __builtin_amdgcn_global_load_lds(
      (const __attribute__((address_space(1))) unsigned int*)g,
      (__attribute__((address_space(3))) unsigned int*)l, 16, 0, 0);
}

// ---------------- weight transpose + cast: W[K][N] f32 -> WT[N][K] bf16 ----
__global__ void tcast_kernel(const float* __restrict__ W, ushort_t* __restrict__ WT,
                             int K, int N) {
  __shared__ float tile[32][33];
  int tx = threadIdx.x & 31, ty = threadIdx.x >> 5;
  int n0 = blockIdx.x * 32, k0 = blockIdx.y * 32;
#pragma unroll
  for (int r = 0; r < 4; ++r)
    tile[ty + 8*r][tx] = W[(size_t)(k0 + ty + 8*r) * N + n0 + tx];
  __syncthreads();
#pragma unroll
  for (int r = 0; r < 4; ++r)
    WT[(size_t)(n0 + ty + 8*r) * K + k0 + tx] = f2bf(tile[tx][ty + 8*r]);
}

// ---------------- V transpose: qkv[row][2048+h*64+d] -> vT[bh][d][kv] ------
__global__ __launch_bounds__(256) void vtrans_kernel(
    const ushort_t* __restrict__ qkvb, ushort_t* __restrict__ vT) {
  __shared__ ushort_t tile[128][66];   // pad 66: conflict-light transpose
  int bh = blockIdx.x;                 // 0..127
  int kt = blockIdx.y;                 // 0..7 (128 kv rows each)
  int b = bh >> 4, h = bh & 15;
  int tid = threadIdx.x;
#pragma unroll
  for (int i = 0; i < 4; ++i) {
    int flat = tid + 256 * i;          // 1024 chunks of 8 elems
    int r = flat >> 3, c8 = flat & 7;
    bf16x8 v = *(const bf16x8*)((const short*)qkvb +
        (size_t)(b * LSEQ + kt * 128 + r) * 3072 + 2048 + h * 64 + c8 * 8);
#pragma unroll
    for (int j = 0; j < 8; ++j) tile[r][c8 * 8 + j] = (ushort_t)v[j];
  }
  __syncthreads();
#pragma unroll
  for (int i = 0; i < 4; ++i) {
    int d = i * 16 + (tid >> 4);
    int kc = tid & 15;
    bf16x8 ov;
#pragma unroll
    for (int j = 0; j < 8; ++j) ov[j] = (short)tile[kc * 8 + j][d];
    *(bf16x8*)((short*)vT + (size_t)(bh * 64 + d) * 1024 + kt * 128 + kc * 8) = ov;
  }
}

// ---------------- adaLN: ssg[b][j] = silu(c[b]) @ ada_w[:,j] + ada_b[j] ----
__global__ void ada_kernel(const float* __restrict__ c, const float* __restrict__ ada_w,
                           const float* __restrict__ ada_b, float* __restrict__ ssg) {
  __shared__ float s[DMODEL];
  int b = blockIdx.y;
  int j = blockIdx.x * 256 + threadIdx.x;
  for (int i = threadIdx.x; i < DMODEL; i += 256) {
    float v = c[b * DMODEL + i];
    s[i] = v / (1.0f + __expf(-v));
  }
  __syncthreads();
  float acc = ada_b[j];
#pragma unroll 8
  for (int k = 0; k < DMODEL; ++k)
    acc = fmaf(s[k], ada_w[(size_t)k * SIXD + j], acc);
  ssg[b * SIXD + j] = acc;
}

// ---------------- LayerNorm + modulate + cast to bf16 ---------------------
__global__ __launch_bounds__(256) void ln_mod_kernel(
    const float* __restrict__ xin, const float* __restrict__ lw,
    const float* __restrict__ lb, const float* __restrict__ ssg,
    int shift_off, int scale_off, ushort_t* __restrict__ outB) {
  int row = blockIdx.x;
  int b = row >> 10;
  int tid = threadIdx.x;
  float4 v = ((const float4*)xin)[(size_t)row * 256 + tid];
  float sum = v.x + v.y + v.z + v.w;
  float sq  = v.x*v.x + v.y*v.y + v.z*v.z + v.w*v.w;
#pragma unroll
  for (int m = 32; m; m >>= 1) { sum += __shfl_xor(sum, m); sq += __shfl_xor(sq, m); }
  __shared__ float rbuf[8];
  int w = tid >> 6, lane = tid & 63;
  if (lane == 0) { rbuf[w] = sum; rbuf[4 + w] = sq; }
  __syncthreads();
  sum = rbuf[0] + rbuf[1] + rbuf[2] + rbuf[3];
  sq  = rbuf[4] + rbuf[5] + rbuf[6] + rbuf[7];
  float mu  = sum * (1.0f / 1024.0f);
  float var = sq * (1.0f / 1024.0f) - mu * mu;
  float rs  = rsqrtf(var + 1e-5f);
  const float* sg = ssg + b * SIXD;
  float vv[4] = {v.x, v.y, v.z, v.w};
  ushort4 pk;
  unsigned short* pks = (unsigned short*)&pk;
#pragma unroll
  for (int j = 0; j < 4; ++j) {
    int d = tid * 4 + j;
    float h = (vv[j] - mu) * rs * lw[d] + lb[d];
    h = h * (1.0f + sg[scale_off + d]) + sg[shift_off + d];
    pks[j] = f2bf(h);
  }
  ((ushort4*)outB)[(size_t)row * 256 + tid] = pk;
}

// ---------------- GEMM: C[M][N] = A[M][K]bf16 @ BT[N][K]bf16^T + epilogue --
template <int EPI>
__global__ __launch_bounds__(256, 2) void gemm_kernel(
    const ushort_t* __restrict__ A, const ushort_t* __restrict__ BT,
    const float* __restrict__ bias, const float* __restrict__ ssg,
    const float* resid, float* outF, ushort_t* __restrict__ outB,
    int N, int K, int gate_off) {
  __shared__ __align__(16) char As[16384];
  __shared__ __align__(16) char Bs[16384];
  int tid = threadIdx.x, lane = tid & 63, w = tid >> 6;
  int l15 = lane & 15, g = lane >> 4;
  int m0 = blockIdx.y * 128, n0 = blockIdx.x * 128;
  int wrow = (w >> 1) * 64, wcol = (w & 1) * 64;
  f32x4 zero = {0.f, 0.f, 0.f, 0.f};
  f32x4 acc[4][4];
#pragma unroll
  for (int i = 0; i < 4; ++i)
#pragma unroll
    for (int j = 0; j < 4; ++j) acc[i][j] = zero;

  for (int k0 = 0; k0 < K; k0 += 64) {
#pragma unroll
    for (int p = 0; p < 4; ++p) {
      int flat = p * 4096 + w * 1024 + lane * 16;
      int row = flat >> 7;
      int colb = (flat & 127) ^ ((row & 7) << 4);   // inverse-swizzled source
      gload_lds16((const char*)A  + ((size_t)(m0 + row) * K + k0) * 2 + colb,
                  As + p * 4096 + w * 1024);
      gload_lds16((const char*)BT + ((size_t)(n0 + row) * K + k0) * 2 + colb,
                  Bs + p * 4096 + w * 1024);
    }
    __syncthreads();
#pragma unroll
    for (int kk = 0; kk < 2; ++kk) {
      bf16x8 af[4], bfr[4];
#pragma unroll
      for (int i = 0; i < 4; ++i) {
        int ar = wrow + i * 16 + l15;
        af[i]  = *(const bf16x8*)(As + ar * 128 + ((kk * 64 + g * 16) ^ ((ar & 7) << 4)));
        int br = wcol + i * 16 + l15;
        bfr[i] = *(const bf16x8*)(Bs + br * 128 + ((kk * 64 + g * 16) ^ ((br & 7) << 4)));
      }
#pragma unroll
      for (int i = 0; i < 4; ++i)
#pragma unroll
        for (int j = 0; j < 4; ++j)
          acc[i][j] = __builtin_amdgcn_mfma_f32_16x16x32_bf16(af[i], bfr[j], acc[i][j], 0, 0, 0);
    }
    __syncthreads();
  }
  // epilogue
#pragma unroll
  for (int i = 0; i < 4; ++i)
#pragma unroll
    for (int j = 0; j < 4; ++j)
#pragma unroll
      for (int r = 0; r < 4; ++r) {
        int grow = m0 + wrow + i * 16 + g * 4 + r;
        int gcol = n0 + wcol + j * 16 + l15;
        float v = acc[i][j][r] + bias[gcol];
        if (EPI == 0) {
          outB[(size_t)grow * N + gcol] = f2bf(v);
        } else if (EPI == 1 || EPI == 3) {
          int bb = grow >> 10;
          float gate = ssg[bb * SIXD + gate_off + gcol];
          size_t idx = (size_t)grow * N + gcol;   // N==1024 here
          outF[idx] = resid[idx] + gate * v;
        } else {  // gelu tanh-approx
          float u = v;
          float t = 0.7978845608028654f * (u + 0.044715f * u * u * u);
          float e = __expf(2.0f * t);
          float th = 1.0f - 2.0f / (e + 1.0f);
          outB[(size_t)grow * N + gcol] = f2bf(0.5f * u * (1.0f + th));
        }
      }
}

// ---------------- flash attention (swapped QK^T, in-reg P, gload V^T) -----
// grid (16 q-tiles of 64 rows, 128 b*h), 256 threads (4 waves x 16 q-rows).
// K and V^T both staged via global_load_lds (pre-swizzled source, verified
// pattern); P stays in registers (cvt_pk + shfl exchange, verified r5).
__global__ __launch_bounds__(256, 2) void attn_kernel(
    const ushort_t* __restrict__ qkv,   // [8192][3072] bf16 (q|k|v)
    const ushort_t* __restrict__ vT,    // [128 bh][64 d][1024 kv] bf16
    ushort_t* __restrict__ aout) {      // [8192][1024] bf16
  // K dbuf [0,16384) ; V^T dbuf [16384,32768) ; alpha [32768,+256)
  __shared__ __align__(16) char SM[33024];
  float* alphab = (float*)(SM + 32768);
  int tid = threadIdx.x, lane = tid & 63, w = tid >> 6;
  int l15 = lane & 15, g = lane >> 4;
  int qt = blockIdx.x, bh = blockIdx.y;
  int b = bh >> 4, h = bh & 15;

  // Q fragments (B operand): lane holds Q[q = w*16 + l15][d = ks*32 + g*8 + j]
  bf16x8 aq[2];
  {
    int qrow = qt * 64 + w * 16 + l15;
    const short* qp = (const short*)qkv + (size_t)(b * LSEQ + qrow) * 3072 + h * 64 + g * 8;
    aq[0] = *(const bf16x8*)qp;
    aq[1] = *(const bf16x8*)(qp + 32);
  }

  // staging sources (pre-swizzled; tile-invariant part)
  const char* ksrc[2];   // K rows = kv (stride 3072*2 B)
  const char* vsrc[2];   // V^T rows = d (stride 1024*2 B), col = kv*2 bytes
#pragma unroll
  for (int p = 0; p < 2; ++p) {
    int flat = p * 4096 + w * 1024 + lane * 16;
    int row = flat >> 7;
    int colb = (flat & 127) ^ ((row & 7) << 4);
    ksrc[p] = (const char*)qkv + ((size_t)(b * LSEQ + row) * 3072 + 1024 + h * 64) * 2 + colb;
    vsrc[p] = (const char*)vT + ((size_t)(bh * 64 + row) * 1024) * 2 + colb;
  }

  f32x4 zero = {0.f, 0.f, 0.f, 0.f};
  f32x4 o[4] = {zero, zero, zero, zero};
  float mrow = -INFINITY;   // running max in log2-units (scaled)
  float lrow = 0.f;
  const float sc = 0.18033688f;  // (1/sqrt(64)) * log2(e)

  // prologue: stage K0 + V^T0 into buffer 0
#pragma unroll
  for (int p = 0; p < 2; ++p) {
    gload_lds16(ksrc[p], SM + p * 4096 + w * 1024);
    gload_lds16(vsrc[p], SM + 16384 + p * 4096 + w * 1024);
  }
  __syncthreads();

  for (int t = 0; t < 16; ++t) {
    int cur = t & 1;
    if (t < 15) {   // prefetch tile t+1 into other buffer
      size_t koff = (size_t)(t + 1) * (64 * 3072 * 2);
      size_t voff = (size_t)(t + 1) * 128;           // 64 kv * 2 B
#pragma unroll
      for (int p = 0; p < 2; ++p) {
        gload_lds16(ksrc[p] + koff, SM + (cur ^ 1) * 8192 + p * 4096 + w * 1024);
        gload_lds16(vsrc[p] + voff, SM + 16384 + (cur ^ 1) * 8192 + p * 4096 + w * 1024);
      }
    }
    // ---- S^T = K @ Q^T : 8 mfma, A = K-frag (rows=keys), B = Q ----
    f32x4 s4[4] = {zero, zero, zero, zero};
#pragma unroll
    for (int c = 0; c < 4; ++c)
#pragma unroll
      for (int ks = 0; ks < 2; ++ks) {
        int key = c * 16 + l15;
        bf16x8 ak = *(const bf16x8*)(SM + cur * 8192 + key * 128 +
                                     ((ks * 64 + g * 16) ^ ((key & 7) << 4)));
        s4[c] = __builtin_amdgcn_mfma_f32_16x16x32_bf16(ak, aq[ks], s4[c], 0, 0, 0);
      }
    // ---- online softmax: lane owns q = l15; reduce over 4 g-lanes ----
    float z[16], mx = -INFINITY;
#pragma unroll
    for (int c = 0; c < 4; ++c)
#pragma unroll
      for (int r = 0; r < 4; ++r) {
        float t2 = s4[c][r] * sc;
        z[c * 4 + r] = t2;
        mx = fmaxf(mx, t2);
      }
    mx = fmaxf(mx, __shfl_xor(mx, 16));
    mx = fmaxf(mx, __shfl_xor(mx, 32));
    bool need = __any(mx > mrow);
    if (need) {
      float mnew = fmaxf(mrow, mx);
      float alpha = exp2f(mrow - mnew);
      mrow = mnew;
      if (lane < 16) alphab[w * 16 + lane] = alpha;
      lrow *= alpha;
    }
    float p16[16], sump = 0.f;
#pragma unroll
    for (int i = 0; i < 16; ++i) {
      float p = exp2f(z[i] - mrow);
      p16[i] = p;
      sump += p;
    }
    sump += __shfl_xor(sump, 16);
    sump += __shfl_xor(sump, 32);
    lrow += sump;
    if (need) {
      f32x4 av = *(const f32x4*)&alphab[w * 16 + g * 4];
#pragma unroll
      for (int nb = 0; nb < 4; ++nb)
#pragma unroll
        for (int r = 0; r < 4; ++r) o[nb][r] *= av[r];
    }
    // ---- pack P to bf16 pairs: pk[c*2+m] = (P[r=2m+1]<<16)|P[r=2m] ----
    unsigned pk[8];
#pragma unroll
    for (int c = 0; c < 4; ++c)
#pragma unroll
      for (int m = 0; m < 2; ++m)
        asm("v_cvt_pk_bf16_f32 %0, %1, %2"
            : "=v"(pk[c * 2 + m]) : "v"(p16[c * 4 + 2 * m]), "v"(p16[c * 4 + 2 * m + 1]));
    // ---- exchange: build PV A-frags (lane q = l15, k = kb*32 + g*8 + j) ----
    unsigned pa[2][4];
    int gl = (g & 1) * 2;
#pragma unroll
    for (int kb = 0; kb < 2; ++kb)
#pragma unroll
      for (int wv = 0; wv < 4; ++wv) {
        int srcl = l15 + (gl + (wv >> 1)) * 16;
        unsigned vA = (unsigned)__shfl((int)pk[kb * 4 + (wv & 1)], srcl);
        unsigned vB = (unsigned)__shfl((int)pk[kb * 4 + 2 + (wv & 1)], srcl);
        pa[kb][wv] = (g >> 1) ? vB : vA;
      }
    // ---- O += P @ V (bv: swizzled b128 reads of V^T tile) ----
    union PU { unsigned u[4]; bf16x8 v; };
    PU pu0, pu1;
#pragma unroll
    for (int i = 0; i < 4; ++i) { pu0.u[i] = pa[0][i]; pu1.u[i] = pa[1][i]; }
#pragma unroll
    for (int kb = 0; kb < 2; ++kb)
#pragma unroll
      for (int nb = 0; nb < 4; ++nb) {
        int d = nb * 16 + l15;
        bf16x8 bv = *(const bf16x8*)(SM + 16384 + cur * 8192 + d * 128 +
                                     ((kb * 64 + g * 16) ^ ((d & 7) << 4)));
        o[nb] = __builtin_amdgcn_mfma_f32_16x16x32_bf16(kb ? pu1.v : pu0.v, bv, o[nb], 0, 0, 0);
      }
    __syncthreads();   // drains prefetch (vmcnt); all waves done with cur
  }
  // ---- epilogue: O / l (row-indexed via per-wave LDS broadcast) ----
  if (lane < 16) alphab[w * 16 + lane] = 1.0f / lrow;
  f32x4 rl = *(const f32x4*)&alphab[w * 16 + g * 4];
#pragma unroll
  for (int nb = 0; nb < 4; ++nb)
#pragma unroll
    for (int r = 0; r < 4; ++r) {
      int qrow = qt * 64 + w * 16 + g * 4 + r;
      aout[(size_t)(b * LSEQ + qrow) * 1024 + h * 64 + nb * 16 + l15] =
          f2bf(o[nb][r] * rl[r]);
    }
}

// ---------------- launch ---------------------------------------------------
extern "C" void kernel_launch(void* const* d_in, const int* in_sizes, int n_in,
                              void* d_out, int out_size, void* d_ws, size_t ws_size,
                              hipStream_t stream) {
  const float* x      = (const float*)d_in[0];
  const float* c      = (const float*)d_in[1];
  const float* ln1_w  = (const float*)d_in[2];
  const float* ln1_b  = (const float*)d_in[3];
  const float* ln2_w  = (const float*)d_in[4];
  const float* ln2_b  = (const float*)d_in[5];
  const float* ada_w  = (const float*)d_in[6];
  const float* ada_b  = (const float*)d_in[7];
  const float* qkv_w  = (const float*)d_in[8];
  const float* qkv_b  = (const float*)d_in[9];
  const float* proj_w = (const float*)d_in[10];
  const float* proj_b = (const float*)d_in[11];
  const float* fc1_w  = (const float*)d_in[12];
  const float* fc1_b  = (const float*)d_in[13];
  const float* fc2_w  = (const float*)d_in[14];
  const float* fc2_b  = (const float*)d_in[15];
  float* out = (float*)d_out;
  char* ws = (char*)d_ws;

  // workspace layout (bytes); high-water = 109,248,512 (~104.2 MB)
  ushort_t* qkvT  = (ushort_t*)(ws + 0);          // [3072][1024] bf16   6.0 MB
  ushort_t* projT = (ushort_t*)(ws + 6291456);    // [1024][1024]        2.0 MB
  ushort_t* fc1T  = (ushort_t*)(ws + 8388608);    // [4096][1024]        8.0 MB
  ushort_t* fc2T  = (ushort_t*)(ws + 16777216);   // [1024][4096]        8.0 MB
  float*    ssg   = (float*)(ws + 25165824);      // [8][6144] f32       0.2 MB
  ushort_t* hbuf  = (ushort_t*)(ws + 25362432);   // [8192][1024] bf16  16.0 MB
  ushort_t* abuf  = hbuf;                         // alias (ln1 out dead by then)
  ushort_t* qkvb  = (ushort_t*)(ws + 42139648);   // [8192][4096] max   64.0 MB
  // vT occupies the top 16 MB of the qkvb slab (qkv uses only 48 MB of it;
  // the 64 MB gelu reuse happens after attn, when vT is dead).
  ushort_t* vTb   = (ushort_t*)(ws + 92471296);   // [128][64][1024]    16.0 MB
  if (ws_size < (size_t)109248512) return;        // guard: avoid OOB -> GPU fault

  tcast_kernel<<<dim3(96, 32),  256, 0, stream>>>(qkv_w,  qkvT, 1024, 3072);
  tcast_kernel<<<dim3(32, 32),  256, 0, stream>>>(proj_w, projT, 1024, 1024);
  tcast_kernel<<<dim3(128, 32), 256, 0, stream>>>(fc1_w,  fc1T, 1024, 4096);
  tcast_kernel<<<dim3(32, 128), 256, 0, stream>>>(fc2_w,  fc2T, 4096, 1024);
  ada_kernel<<<dim3(24, 8), 256, 0, stream>>>(c, ada_w, ada_b, ssg);

  ln_mod_kernel<<<8192, 256, 0, stream>>>(x, ln1_w, ln1_b, ssg, 0, 1024, hbuf);
  gemm_kernel<0><<<dim3(24, 64), 256, 0, stream>>>(hbuf, qkvT, qkv_b, nullptr,
                                                   nullptr, nullptr, qkvb, 3072, 1024, 0);
  vtrans_kernel<<<dim3(128, 8), 256, 0, stream>>>(qkvb, vTb);
  attn_kernel<<<dim3(16, 128), 256, 0, stream>>>(qkvb, vTb, abuf);
  gemm_kernel<1><<<dim3(8, 64), 256, 0, stream>>>(abuf, projT, proj_b, ssg,
                                                  x, out, nullptr, 1024, 1024, 2048);
  ln_mod_kernel<<<8192, 256, 0, stream>>>(out, ln2_w, ln2_b, ssg, 3072, 4096, hbuf);
  gemm_kernel<2><<<dim3(32, 64), 256, 0, stream>>>(hbuf, fc1T, fc1_b, nullptr,
                                                   nullptr, nullptr, qkvb, 4096, 1024, 0);
  gemm_kernel<3><<<dim3(8, 64), 256, 0, stream>>>(qkvb, fc2T, fc2_b, ssg,
                                                  out, out, nullptr, 1024, 4096, 5120);
}